// Round 1
// baseline (1060.081 us; speedup 1.0000x reference)
//
#include <hip/hip_runtime.h>
#include <cstddef>
#include <cstdint>

#define TCNT 256

namespace {
constexpr int CIN    = 64;
constexpr int COUT   = 128;
constexpr int HDIM   = 64;
constexpr int WDIM   = 64;
constexpr int HW     = HDIM * WDIM;     // 4096
constexpr int KD     = CIN * 9;         // 576
constexpr int NOFF   = 2 * CIN * 9;     // 1152
constexpr int NTOT   = NOFF + CIN * 9;  // 1728
constexpr int NBATCH = 8;
constexpr float MAXOFF = 16.0f;         // max(H,W)/4
}

// ---------------------------------------------------------------------------
// Stage 1: offset + mask 3x3 convs as one implicit-GEMM.
//   ws[co][p] = clip/bias( sum_k W[co][k] * im2col(x)[p][k] )
//   k = c*9 + ki*3 + kj ; co<1152 -> offset (clipped +-16), else mask.
//   ws is plane-major: plane stride = nb*4096 (chunk-local pixels).
// ---------------------------------------------------------------------------
__global__ __launch_bounds__(TCNT) void dcn_stage1(
    const float* __restrict__ x, const float* __restrict__ w_off,
    const float* __restrict__ b_off, const float* __restrict__ w_mod,
    const float* __restrict__ b_mod, float* __restrict__ ws,
    int b0, int nb)
{
  __shared__ float As[32][132];
  __shared__ float Bs[32][132];

  const int t      = threadIdx.x;
  const int Mchunk = nb * HW;
  const int p0  = blockIdx.x * 128;          // chunk-local pixel base (2 rows)
  const int b   = b0 + (p0 >> 12);
  const int h0  = (p0 & (HW - 1)) >> 6;
  const int co0 = blockIdx.y * 128;

  const int tx = t & 15;                     // pixel octet
  const int ty = t >> 4;                     // co octet

  const int a_tp = t & 127;
  const int a_tk = t >> 7;                   // 0..1
  const int a_w  = a_tp & 63;
  const int a_hi = a_tp >> 6;

  const int b_tk = t & 7;
  const int b_tc = t >> 3;                   // 0..31

  float acc[8][8];
  #pragma unroll
  for (int i = 0; i < 8; ++i)
    #pragma unroll
    for (int j = 0; j < 8; ++j) acc[i][j] = 0.f;

  const float* xb = x + (size_t)b * CIN * HW;

  #pragma unroll 1
  for (int k0 = 0; k0 < KD; k0 += 32) {
    // A tile: As[kl][pixel]  (im2col on the fly, coalesced x-row loads)
    #pragma unroll
    for (int i = 0; i < 16; ++i) {
      const int kl = a_tk * 16 + i;
      const int k  = k0 + kl;
      const int c  = k / 9;
      const int r  = k - c * 9;
      const int ki = r / 3;
      const int kj = r - ki * 3;
      const int yy = h0 + a_hi + ki - 1;
      const int xx = a_w + kj - 1;
      float v = 0.f;
      if ((unsigned)yy < (unsigned)HDIM && (unsigned)xx < (unsigned)WDIM)
        v = xb[((c << 6) + yy) * WDIM + xx];
      As[kl][a_tp] = v;
    }
    // B tile: Bs[kl][co_local]  (float4 rows, coalesced)
    #pragma unroll
    for (int q = 0; q < 4; ++q) {
      const int col = b_tc + q * 32;
      const int cog = co0 + col;
      float4 wv = make_float4(0.f, 0.f, 0.f, 0.f);
      if (cog < NTOT) {
        const float* wrow = (cog < NOFF) ? (w_off + (size_t)cog * KD)
                                         : (w_mod + (size_t)(cog - NOFF) * KD);
        wv = *(const float4*)(wrow + k0 + b_tk * 4);
      }
      Bs[b_tk * 4 + 0][col] = wv.x;
      Bs[b_tk * 4 + 1][col] = wv.y;
      Bs[b_tk * 4 + 2][col] = wv.z;
      Bs[b_tk * 4 + 3][col] = wv.w;
    }
    __syncthreads();
    #pragma unroll 4
    for (int kk = 0; kk < 32; ++kk) {
      float a[8], w[8];
      *(float4*)&a[0] = *(const float4*)&As[kk][tx * 8];
      *(float4*)&a[4] = *(const float4*)&As[kk][tx * 8 + 4];
      *(float4*)&w[0] = *(const float4*)&Bs[kk][ty * 8];
      *(float4*)&w[4] = *(const float4*)&Bs[kk][ty * 8 + 4];
      #pragma unroll
      for (int i = 0; i < 8; ++i)
        #pragma unroll
        for (int j = 0; j < 8; ++j)
          acc[i][j] += a[i] * w[j];
    }
    __syncthreads();
  }

  // Epilogue: bias, clip (offset part), store plane-major.
  #pragma unroll
  for (int j = 0; j < 8; ++j) {
    const int cog = co0 + ty * 8 + j;
    if (cog >= NTOT) continue;
    const bool  isOff = cog < NOFF;
    const float bias  = isOff ? b_off[cog] : b_mod[cog - NOFF];
    float vv[8];
    #pragma unroll
    for (int i = 0; i < 8; ++i) {
      float v = acc[i][j] + bias;
      if (isOff) v = fminf(MAXOFF, fmaxf(-MAXOFF, v));
      vv[i] = v;
    }
    float* orow = ws + (size_t)cog * Mchunk + p0 + tx * 8;
    *(float4*)(orow)     = make_float4(vv[0], vv[1], vv[2], vv[3]);
    *(float4*)(orow + 4) = make_float4(vv[4], vv[5], vv[6], vv[7]);
  }
}

// ---------------------------------------------------------------------------
// Stage 2: bilinear deform-sampling + output einsum, fused.
//   Block = one image row (64 px) x all 128 output channels.
//   9 chunks of 64 K-values: phase A -> samp LDS, phase B -> FMA vs wlds.
// ---------------------------------------------------------------------------
__global__ __launch_bounds__(TCNT) void dcn_stage2(
    const float* __restrict__ x, const float* __restrict__ ws,
    const float* __restrict__ w_conv, float* __restrict__ out,
    int b0, int nb)
{
  __shared__ float samp[64][68];
  __shared__ float wlds[128][68];

  const int t      = threadIdx.x;
  const int Mchunk = nb * HW;
  const int pc0 = blockIdx.x * 64;           // one image row, chunk-local
  const int b   = b0 + (pc0 >> 12);
  const int h   = (pc0 & (HW - 1)) >> 6;

  const int tpx = t & 63;                    // pixel (w coordinate)
  const int tsg = t >> 6;                    // 0..3
  const float* ws_pix = ws + pc0 + tpx;
  const float* xb     = x + (size_t)b * CIN * HW;

  const int tp2 = t & 15;
  const int to  = t >> 4;                    // 0..15

  float acc[4][8];
  #pragma unroll
  for (int i = 0; i < 4; ++i)
    #pragma unroll
    for (int j = 0; j < 8; ++j) acc[i][j] = 0.f;

  #pragma unroll 1
  for (int sc = 0; sc < 9; ++sc) {
    __syncthreads();   // previous phase B done before overwriting samp/wlds
    // ---- phase A: samples for s in [sc*64, sc*64+64), s = c*9 + kk
    #pragma unroll 4
    for (int j = 0; j < 16; ++j) {
      const int sl = tsg + 4 * j;
      const int s  = sc * 64 + sl;
      const int c  = s / 9;
      const int kk = s - c * 9;
      const int ki = kk / 3;
      const int kj = kk - ki * 3;
      const float dy = ws_pix[(size_t)(2 * s)     * Mchunk];
      const float dx = ws_pix[(size_t)(2 * s + 1) * Mchunk];
      const float m  = ws_pix[(size_t)(NOFF + s)  * Mchunk];
      const float py = dy + (float)(h   + ki - 1);
      const float px = dx + (float)(tpx + kj - 1);
      const bool valid = (py > -1.f) && (py < (float)HDIM) &&
                         (px > -1.f) && (px < (float)WDIM);
      const float y0f = floorf(py), x0f = floorf(px);
      const float wy = py - y0f, wx = px - x0f;
      const int y0 = (int)y0f, x0 = (int)x0f;
      const float* plane = xb + c * HW;
      float v00 = 0.f, v01 = 0.f, v10 = 0.f, v11 = 0.f;
      if ((unsigned)y0 < (unsigned)HDIM) {
        const float* row = plane + (y0 << 6);
        if ((unsigned)x0       < (unsigned)WDIM) v00 = row[x0];
        if ((unsigned)(x0 + 1) < (unsigned)WDIM) v01 = row[x0 + 1];
      }
      if ((unsigned)(y0 + 1) < (unsigned)HDIM) {
        const float* row = plane + ((y0 + 1) << 6);
        if ((unsigned)x0       < (unsigned)WDIM) v10 = row[x0];
        if ((unsigned)(x0 + 1) < (unsigned)WDIM) v11 = row[x0 + 1];
      }
      const float val = (1.f - wy) * ((1.f - wx) * v00 + wx * v01)
                      + wy         * ((1.f - wx) * v10 + wx * v11);
      samp[tpx][sl] = valid ? val * m : 0.f;
    }
    // ---- stage w_conv chunk: wlds[o][0..63] = w_conv[o][sc*64 .. +63]
    #pragma unroll
    for (int i = 0; i < 8; ++i) {
      const int lin = t + TCNT * i;          // 0..2047
      const int o   = lin >> 4;
      const int f4  = (lin & 15) << 2;
      *(float4*)&wlds[o][f4] =
          *(const float4*)(w_conv + (size_t)o * KD + sc * 64 + f4);
    }
    __syncthreads();
    // ---- phase B: acc[px_rep][o_rep] += samp . wlds
    #pragma unroll 4
    for (int s4 = 0; s4 < 16; ++s4) {
      float4 av[4];
      #pragma unroll
      for (int i = 0; i < 4; ++i)
        av[i] = *(const float4*)&samp[tp2 + 16 * i][s4 * 4];
      #pragma unroll
      for (int j = 0; j < 8; ++j) {
        const float4 wv = *(const float4*)&wlds[to + 16 * j][s4 * 4];
        #pragma unroll
        for (int i = 0; i < 4; ++i)
          acc[i][j] += av[i].x * wv.x + av[i].y * wv.y
                     + av[i].z * wv.z + av[i].w * wv.w;
      }
    }
  }

  #pragma unroll
  for (int j = 0; j < 8; ++j) {
    const int o = to + 16 * j;
    float* orow = out + ((size_t)(b * COUT + o)) * HW + h * WDIM;
    #pragma unroll
    for (int i = 0; i < 4; ++i)
      orow[tp2 + 16 * i] = acc[i][j];
  }
}

// ---------------------------------------------------------------------------
extern "C" void kernel_launch(void* const* d_in, const int* in_sizes, int n_in,
                              void* d_out, int out_size, void* d_ws, size_t ws_size,
                              hipStream_t stream) {
  (void)in_sizes; (void)n_in; (void)out_size;
  const float* x      = (const float*)d_in[0];
  const float* w_off  = (const float*)d_in[1];
  const float* b_off  = (const float*)d_in[2];
  const float* w_mod  = (const float*)d_in[3];
  const float* b_mod  = (const float*)d_in[4];
  const float* w_conv = (const float*)d_in[5];
  float* out = (float*)d_out;
  float* ws  = (float*)d_ws;

  // Workspace: 1728 planes x (nb*4096) pixels, chunked over batches if small.
  const size_t ws_per_batch = (size_t)NTOT * HW * sizeof(float);  // 28.3 MB
  int nb = (int)(ws_size / ws_per_batch);
  if (nb < 1) nb = 1;
  if (nb > NBATCH) nb = NBATCH;

  for (int b0 = 0; b0 < NBATCH; b0 += nb) {
    const int cur = (NBATCH - b0 < nb) ? (NBATCH - b0) : nb;
    dim3 g1(cur * 32, 14);   // pixel tiles x co tiles (14*128 = 1792 >= 1728)
    dcn_stage1<<<g1, TCNT, 0, stream>>>(x, w_off, b_off, w_mod, b_mod, ws, b0, cur);
    dcn_stage2<<<cur * 64, TCNT, 0, stream>>>(x, ws, w_conv, out, b0, cur);
  }
}

// Round 2
// 824.707 us; speedup vs baseline: 1.2854x; 1.2854x over previous
//
#include <hip/hip_runtime.h>
#include <cstddef>
#include <cstdint>

#define TCNT 256

namespace {
constexpr int CIN    = 64;
constexpr int COUT   = 128;
constexpr int HDIM   = 64;
constexpr int WDIM   = 64;
constexpr int HW     = HDIM * WDIM;     // 4096
constexpr int KD     = CIN * 9;         // 576
constexpr int NOFF   = 2 * CIN * 9;     // 1152
constexpr int NTOT   = NOFF + CIN * 9;  // 1728
constexpr int NBATCH = 8;
constexpr float MAXOFF = 16.0f;         // max(H,W)/4
}

typedef __attribute__((ext_vector_type(8))) short s16x8;
typedef __attribute__((ext_vector_type(4))) float f32x4;

__device__ __forceinline__ unsigned short f2bf(float v) {
  unsigned u = __builtin_bit_cast(unsigned, v);
  unsigned r = u + 0x7fffu + ((u >> 16) & 1u);   // RNE
  return (unsigned short)(r >> 16);
}
__device__ __forceinline__ float bf2f(unsigned short h) {
  unsigned u = ((unsigned)h) << 16;
  return __builtin_bit_cast(float, u);
}

// ---------------------------------------------------------------------------
// Stage 1: offset + mask 3x3 convs as one implicit-GEMM on MFMA (split-bf16).
//   C[p][co] = sum_k im2col(x)[p][k] * W[co][k],  fp32-grade via hi/lo bf16
//   (3 MFMA per product: ah*bh + ah*bl + al*bh).
//   128x128 tile, BK=32, 4 waves (2x2), 16x16x32 bf16 MFMA.
//   ws is plane-major: ws[co][p], plane stride = nb*4096.
// ---------------------------------------------------------------------------
__global__ __launch_bounds__(TCNT) void dcn_stage1(
    const float* __restrict__ x, const float* __restrict__ w_off,
    const float* __restrict__ b_off, const float* __restrict__ w_mod,
    const float* __restrict__ b_mod, float* __restrict__ ws,
    int b0, int nb)
{
  // LDS: 64B row stride (naturally bank-staggered) + XOR slot swizzle.
  __shared__ unsigned short Ah[128][32], Al[128][32];
  __shared__ unsigned short Bh[128][32], Bl[128][32];

  const int t      = threadIdx.x;
  const int Mchunk = nb * HW;
  const int p0  = blockIdx.x * 128;          // chunk-local pixel base (2 rows)
  const int b   = b0 + (p0 >> 12);
  const int h0  = (p0 & (HW - 1)) >> 6;
  const int co0 = blockIdx.y * 128;

  // A-staging role: row = pixel-local, 16 k's per thread.
  const int a_row = t & 127;
  const int a_kh  = t >> 7;                  // 0..1 (which 16-k half)
  const int a_sw  = ((a_row >> 1) & 3) << 3;
  const int a_h   = h0 + (a_row >> 6) - 1;   // + ki later
  const int a_w   = (a_row & 63) - 1;        // + kj later

  // B-staging role: row = co-local, 16 k's per thread.
  const int b_row = t >> 1;
  const int b_kh  = t & 1;
  const int b_sw  = ((b_row >> 1) & 3) << 3;
  const int cog_s = co0 + b_row;
  const float* wrow =
      (cog_s < NOFF) ? (w_off + (size_t)cog_s * KD)
                     : (cog_s < NTOT ? (w_mod + (size_t)(cog_s - NOFF) * KD)
                                     : nullptr);

  // MFMA role.
  const int wave = t >> 6, lane = t & 63;
  const int wm = wave >> 1, wn = wave & 1;
  const int lrow = lane & 15;
  const int lkh  = lane >> 4;                // k-offset = lkh*8

  const float* xb = x + (size_t)b * CIN * HW;

  f32x4 acc[4][4];
  #pragma unroll
  for (int m = 0; m < 4; ++m)
    #pragma unroll
    for (int n = 0; n < 4; ++n) acc[m][n] = (f32x4)0.f;

  float avA[16], bvA[16], avB[16], bvB[16];

#define STAGE_LOAD(AV, BV, K0)                                               \
  {                                                                          \
    _Pragma("unroll")                                                        \
    for (int i = 0; i < 16; ++i) {                                           \
      const unsigned k  = (unsigned)(K0) + (unsigned)a_kh * 16u + (unsigned)i;\
      const unsigned c  = k / 9u;                                            \
      const unsigned rm = k - 9u * c;                                        \
      const unsigned ki = rm / 3u;                                           \
      const unsigned kj = rm - 3u * ki;                                      \
      const int yy = a_h + (int)ki;                                          \
      const int xx = a_w + (int)kj;                                          \
      AV[i] = ((unsigned)yy < 64u && (unsigned)xx < 64u)                     \
                  ? xb[(c << 12) + ((unsigned)yy << 6) + (unsigned)xx]       \
                  : 0.f;                                                     \
    }                                                                        \
    _Pragma("unroll")                                                        \
    for (int q = 0; q < 4; ++q) {                                            \
      if (wrow) *(float4*)&BV[q * 4] =                                       \
          *(const float4*)(wrow + (K0) + b_kh * 16 + q * 4);                 \
      else *(float4*)&BV[q * 4] = make_float4(0.f, 0.f, 0.f, 0.f);           \
    }                                                                        \
  }

#define STAGE_WRITE(AV, BV)                                                  \
  {                                                                          \
    _Pragma("unroll")                                                        \
    for (int s = 0; s < 2; ++s) {                                            \
      s16x8 h8, l8;                                                          \
      _Pragma("unroll")                                                      \
      for (int j = 0; j < 8; ++j) {                                          \
        const float v = AV[s * 8 + j];                                       \
        const unsigned short hb = f2bf(v);                                   \
        h8[j] = (short)hb;                                                   \
        l8[j] = (short)f2bf(v - bf2f(hb));                                   \
      }                                                                      \
      const int cola = (a_kh * 16 + s * 8) ^ a_sw;                           \
      *(s16x8*)&Ah[a_row][cola] = h8;                                        \
      *(s16x8*)&Al[a_row][cola] = l8;                                        \
    }                                                                        \
    _Pragma("unroll")                                                        \
    for (int s = 0; s < 2; ++s) {                                            \
      s16x8 h8, l8;                                                          \
      _Pragma("unroll")                                                      \
      for (int j = 0; j < 8; ++j) {                                          \
        const float v = BV[s * 8 + j];                                       \
        const unsigned short hb = f2bf(v);                                   \
        h8[j] = (short)hb;                                                   \
        l8[j] = (short)f2bf(v - bf2f(hb));                                   \
      }                                                                      \
      const int colb = (b_kh * 16 + s * 8) ^ b_sw;                           \
      *(s16x8*)&Bh[b_row][colb] = h8;                                        \
      *(s16x8*)&Bl[b_row][colb] = l8;                                        \
    }                                                                        \
  }

#define MFMA_PHASE()                                                         \
  {                                                                          \
    s16x8 fah[4], fal[4];                                                    \
    _Pragma("unroll")                                                        \
    for (int m = 0; m < 4; ++m) {                                            \
      const int r   = wm * 64 + m * 16 + lrow;                               \
      const int col = (lkh * 8) ^ (((r >> 1) & 3) << 3);                     \
      fah[m] = *(const s16x8*)&Ah[r][col];                                   \
      fal[m] = *(const s16x8*)&Al[r][col];                                   \
    }                                                                        \
    _Pragma("unroll")                                                        \
    for (int n = 0; n < 4; ++n) {                                            \
      const int r   = wn * 64 + n * 16 + lrow;                               \
      const int col = (lkh * 8) ^ (((r >> 1) & 3) << 3);                     \
      const s16x8 fbh = *(const s16x8*)&Bh[r][col];                          \
      const s16x8 fbl = *(const s16x8*)&Bl[r][col];                          \
      _Pragma("unroll")                                                      \
      for (int m = 0; m < 4; ++m) {                                          \
        acc[m][n] = __builtin_amdgcn_mfma_f32_16x16x32_bf16(fah[m], fbh, acc[m][n], 0, 0, 0); \
        acc[m][n] = __builtin_amdgcn_mfma_f32_16x16x32_bf16(fah[m], fbl, acc[m][n], 0, 0, 0); \
        acc[m][n] = __builtin_amdgcn_mfma_f32_16x16x32_bf16(fal[m], fbh, acc[m][n], 0, 0, 0); \
      }                                                                      \
    }                                                                        \
  }

  STAGE_LOAD(avA, bvA, 0)
  #pragma unroll 1
  for (int dstep = 0; dstep < 9; ++dstep) {
    const int k0 = dstep * 64;
    STAGE_WRITE(avA, bvA)
    STAGE_LOAD(avB, bvB, k0 + 32)      // issue next loads before barrier/MFMA
    __syncthreads();
    MFMA_PHASE()
    __syncthreads();
    STAGE_WRITE(avB, bvB)
    if (dstep < 8) STAGE_LOAD(avA, bvA, k0 + 64)
    __syncthreads();
    MFMA_PHASE()
    __syncthreads();
  }

  // Epilogue: bias, clip (offset region), store plane-major.
  const bool isOff = (co0 < NOFF);           // 128 | 1152 -> block-uniform
  #pragma unroll
  for (int n = 0; n < 4; ++n) {
    const int cog = co0 + wn * 64 + n * 16 + lrow;
    if (cog >= NTOT) continue;
    const float bias = isOff ? b_off[cog] : b_mod[cog - NOFF];
    float* oplane = ws + (size_t)cog * Mchunk;
    #pragma unroll
    for (int m = 0; m < 4; ++m) {
      f32x4 v = acc[m][n];
      float4 o;
      o.x = v[0] + bias; o.y = v[1] + bias; o.z = v[2] + bias; o.w = v[3] + bias;
      if (isOff) {
        o.x = fminf(MAXOFF, fmaxf(-MAXOFF, o.x));
        o.y = fminf(MAXOFF, fmaxf(-MAXOFF, o.y));
        o.z = fminf(MAXOFF, fmaxf(-MAXOFF, o.z));
        o.w = fminf(MAXOFF, fmaxf(-MAXOFF, o.w));
      }
      const int pb = p0 + wm * 64 + m * 16 + lkh * 4;   // reg idx -> +row
      *(float4*)(oplane + pb) = o;
    }
  }
#undef STAGE_LOAD
#undef STAGE_WRITE
#undef MFMA_PHASE
}

// ---------------------------------------------------------------------------
// Stage 2: bilinear deform-sampling + output einsum, fused. (unchanged)
// ---------------------------------------------------------------------------
__global__ __launch_bounds__(TCNT) void dcn_stage2(
    const float* __restrict__ x, const float* __restrict__ ws,
    const float* __restrict__ w_conv, float* __restrict__ out,
    int b0, int nb)
{
  __shared__ float samp[64][68];
  __shared__ float wlds[128][68];

  const int t      = threadIdx.x;
  const int Mchunk = nb * HW;
  const int pc0 = blockIdx.x * 64;           // one image row, chunk-local
  const int b   = b0 + (pc0 >> 12);
  const int h   = (pc0 & (HW - 1)) >> 6;

  const int tpx = t & 63;                    // pixel (w coordinate)
  const int tsg = t >> 6;                    // 0..3
  const float* ws_pix = ws + pc0 + tpx;
  const float* xb     = x + (size_t)b * CIN * HW;

  const int tp2 = t & 15;
  const int to  = t >> 4;                    // 0..15

  float acc[4][8];
  #pragma unroll
  for (int i = 0; i < 4; ++i)
    #pragma unroll
    for (int j = 0; j < 8; ++j) acc[i][j] = 0.f;

  #pragma unroll 1
  for (int sc = 0; sc < 9; ++sc) {
    __syncthreads();   // previous phase B done before overwriting samp/wlds
    // ---- phase A: samples for s in [sc*64, sc*64+64), s = c*9 + kk
    #pragma unroll 4
    for (int j = 0; j < 16; ++j) {
      const int sl = tsg + 4 * j;
      const int s  = sc * 64 + sl;
      const int c  = s / 9;
      const int kk = s - c * 9;
      const int ki = kk / 3;
      const int kj = kk - ki * 3;
      const float dy = ws_pix[(size_t)(2 * s)     * Mchunk];
      const float dx = ws_pix[(size_t)(2 * s + 1) * Mchunk];
      const float m  = ws_pix[(size_t)(NOFF + s)  * Mchunk];
      const float py = dy + (float)(h   + ki - 1);
      const float px = dx + (float)(tpx + kj - 1);
      const bool valid = (py > -1.f) && (py < (float)HDIM) &&
                         (px > -1.f) && (px < (float)WDIM);
      const float y0f = floorf(py), x0f = floorf(px);
      const float wy = py - y0f, wx = px - x0f;
      const int y0 = (int)y0f, x0 = (int)x0f;
      const float* plane = xb + c * HW;
      float v00 = 0.f, v01 = 0.f, v10 = 0.f, v11 = 0.f;
      if ((unsigned)y0 < (unsigned)HDIM) {
        const float* row = plane + (y0 << 6);
        if ((unsigned)x0       < (unsigned)WDIM) v00 = row[x0];
        if ((unsigned)(x0 + 1) < (unsigned)WDIM) v01 = row[x0 + 1];
      }
      if ((unsigned)(y0 + 1) < (unsigned)HDIM) {
        const float* row = plane + ((y0 + 1) << 6);
        if ((unsigned)x0       < (unsigned)WDIM) v10 = row[x0];
        if ((unsigned)(x0 + 1) < (unsigned)WDIM) v11 = row[x0 + 1];
      }
      const float val = (1.f - wy) * ((1.f - wx) * v00 + wx * v01)
                      + wy         * ((1.f - wx) * v10 + wx * v11);
      samp[tpx][sl] = valid ? val * m : 0.f;
    }
    // ---- stage w_conv chunk: wlds[o][0..63] = w_conv[o][sc*64 .. +63]
    #pragma unroll
    for (int i = 0; i < 8; ++i) {
      const int lin = t + TCNT * i;          // 0..2047
      const int o   = lin >> 4;
      const int f4  = (lin & 15) << 2;
      *(float4*)&wlds[o][f4] =
          *(const float4*)(w_conv + (size_t)o * KD + sc * 64 + f4);
    }
    __syncthreads();
    // ---- phase B: acc[px_rep][o_rep] += samp . wlds
    #pragma unroll 4
    for (int s4 = 0; s4 < 16; ++s4) {
      float4 av[4];
      #pragma unroll
      for (int i = 0; i < 4; ++i)
        av[i] = *(const float4*)&samp[tp2 + 16 * i][s4 * 4];
      #pragma unroll
      for (int j = 0; j < 8; ++j) {
        const float4 wv = *(const float4*)&wlds[to + 16 * j][s4 * 4];
        #pragma unroll
        for (int i = 0; i < 4; ++i)
          acc[i][j] += av[i].x * wv.x + av[i].y * wv.y
                     + av[i].z * wv.z + av[i].w * wv.w;
      }
    }
  }

  #pragma unroll
  for (int j = 0; j < 8; ++j) {
    const int o = to + 16 * j;
    float* orow = out + ((size_t)(b * COUT + o)) * HW + h * WDIM;
    #pragma unroll
    for (int i = 0; i < 4; ++i)
      orow[tp2 + 16 * i] = acc[i][j];
  }
}

// ---------------------------------------------------------------------------
extern "C" void kernel_launch(void* const* d_in, const int* in_sizes, int n_in,
                              void* d_out, int out_size, void* d_ws, size_t ws_size,
                              hipStream_t stream) {
  (void)in_sizes; (void)n_in; (void)out_size;
  const float* x      = (const float*)d_in[0];
  const float* w_off  = (const float*)d_in[1];
  const float* b_off  = (const float*)d_in[2];
  const float* w_mod  = (const float*)d_in[3];
  const float* b_mod  = (const float*)d_in[4];
  const float* w_conv = (const float*)d_in[5];
  float* out = (float*)d_out;
  float* ws  = (float*)d_ws;

  // Workspace: 1728 planes x (nb*4096) pixels, chunked over batches if small.
  const size_t ws_per_batch = (size_t)NTOT * HW * sizeof(float);  // 28.3 MB
  int nb = (int)(ws_size / ws_per_batch);
  if (nb < 1) nb = 1;
  if (nb > NBATCH) nb = NBATCH;

  for (int b0 = 0; b0 < NBATCH; b0 += nb) {
    const int cur = (NBATCH - b0 < nb) ? (NBATCH - b0) : nb;
    dim3 g1(cur * 32, 14);   // pixel tiles x co tiles (14*128 = 1792 >= 1728)
    dcn_stage1<<<g1, TCNT, 0, stream>>>(x, w_off, b_off, w_mod, b_mod, ws, b0, cur);
    dcn_stage2<<<cur * 64, TCNT, 0, stream>>>(x, ws, w_conv, out, b0, cur);
  }
}

// Round 3
// 450.197 us; speedup vs baseline: 2.3547x; 1.8319x over previous
//
#include <hip/hip_runtime.h>
#include <cstddef>
#include <cstdint>

#define TCNT 256

namespace {
constexpr int CIN    = 64;
constexpr int COUT   = 128;
constexpr int HDIM   = 64;
constexpr int WDIM   = 64;
constexpr int HW     = HDIM * WDIM;     // 4096
constexpr int KD     = CIN * 9;         // 576
constexpr int NOFF   = 2 * CIN * 9;     // 1152
constexpr int NTOT   = NOFF + CIN * 9;  // 1728
constexpr int NBATCH = 8;
constexpr int HXW    = 66;              // halo-padded spatial dim
constexpr int COPAD  = 1792;            // 14*128 padded co
constexpr float MAXOFF = 16.0f;         // max(H,W)/4

// d_ws layout (ushort elements for the bf16 region, then fp32 planes)
constexpr size_t XT_ELEMS = (size_t)NBATCH * HXW * HXW * 64;  // 2,230,272
constexpr size_t WP_ELEMS = (size_t)9 * COPAD * 64;           // 1,032,192
constexpr size_t OFF_XTH  = 0;
constexpr size_t OFF_XTL  = XT_ELEMS;
constexpr size_t OFF_WPH  = 2 * XT_ELEMS;
constexpr size_t OFF_WPL  = 2 * XT_ELEMS + WP_ELEMS;
constexpr size_t FIXED_BYTES = (2 * XT_ELEMS + 2 * WP_ELEMS) * 2;  // 13,049,856
}

typedef __attribute__((ext_vector_type(8))) short s16x8;
typedef __attribute__((ext_vector_type(4))) float f32x4;

__device__ __forceinline__ unsigned short f2bf(float v) {
  unsigned u = __builtin_bit_cast(unsigned, v);
  unsigned r = u + 0x7fffu + ((u >> 16) & 1u);   // RNE
  return (unsigned short)(r >> 16);
}
__device__ __forceinline__ float bf2f(unsigned short h) {
  unsigned u = ((unsigned)h) << 16;
  return __builtin_bit_cast(float, u);
}

// ---------------------------------------------------------------------------
// prep_x: x fp32 NCHW -> xTh/xTl bf16 hi/lo, HWC layout with zero halo:
//   xT[b][yy 0..65][xx 0..65][c 0..63], yy/xx = image coords + 1.
// ---------------------------------------------------------------------------
__global__ __launch_bounds__(TCNT) void prep_x(
    const float* __restrict__ x, unsigned short* __restrict__ xTh,
    unsigned short* __restrict__ xTl)
{
  const int b  = blockIdx.y;
  const int yy = blockIdx.x;
  const int t  = threadIdx.x;
  unsigned short* oh = xTh + ((size_t)(b * HXW + yy)) * HXW * 64;
  unsigned short* ol = xTl + ((size_t)(b * HXW + yy)) * HXW * 64;
  if (yy == 0 || yy == HXW - 1) {
    for (int lin = t; lin < HXW * 64; lin += TCNT) { oh[lin] = 0; ol[lin] = 0; }
    return;
  }
  __shared__ float tile[64][65];
  const int y = yy - 1;
  #pragma unroll
  for (int i = 0; i < 4; ++i) {
    const int f = t + TCNT * i;          // 0..1023 float4s
    const int c = f >> 4, xq = f & 15;
    const float4 v =
        *(const float4*)(x + ((size_t)(b * 64 + c)) * HW + y * WDIM + xq * 4);
    tile[c][xq * 4 + 0] = v.x; tile[c][xq * 4 + 1] = v.y;
    tile[c][xq * 4 + 2] = v.z; tile[c][xq * 4 + 3] = v.w;
  }
  if (t < 128) {                          // zero halo columns xx=0, xx=65
    const int c = t & 63, xe = (t >> 6) ? (HXW - 1) * 64 : 0;
    oh[xe + c] = 0; ol[xe + c] = 0;
  }
  __syncthreads();
  const int xc = t >> 2, cg = (t & 3) * 16;
  s16x8 h0, h1, l0, l1;
  #pragma unroll
  for (int u = 0; u < 8; ++u) {
    const float v = tile[cg + u][xc];
    const unsigned short hb = f2bf(v);
    h0[u] = (short)hb; l0[u] = (short)f2bf(v - bf2f(hb));
  }
  #pragma unroll
  for (int u = 0; u < 8; ++u) {
    const float v = tile[cg + 8 + u][xc];
    const unsigned short hb = f2bf(v);
    h1[u] = (short)hb; l1[u] = (short)f2bf(v - bf2f(hb));
  }
  *(s16x8*)(oh + (xc + 1) * 64 + cg)     = h0;
  *(s16x8*)(oh + (xc + 1) * 64 + cg + 8) = h1;
  *(s16x8*)(ol + (xc + 1) * 64 + cg)     = l0;
  *(s16x8*)(ol + (xc + 1) * 64 + cg + 8) = l1;
}

// ---------------------------------------------------------------------------
// prep_w: w_off/w_mod fp32 [co][c*9+r] -> wPh/wPl bf16 hi/lo, tap-major:
//   wP[r][co 0..1791][c 0..63], co>=1728 zero-filled.
// ---------------------------------------------------------------------------
__global__ __launch_bounds__(TCNT) void prep_w(
    const float* __restrict__ w_off, const float* __restrict__ w_mod,
    unsigned short* __restrict__ wPh, unsigned short* __restrict__ wPl)
{
  const int co = blockIdx.x;
  const int t  = threadIdx.x;
  const float* wrow = (co < NOFF) ? (w_off + (size_t)co * KD)
                    : (co < NTOT) ? (w_mod + (size_t)(co - NOFF) * KD)
                                  : nullptr;
  for (int lin = t; lin < KD; lin += TCNT) {
    const int r = lin >> 6, c = lin & 63;
    const float v = wrow ? wrow[c * 9 + r] : 0.f;
    const unsigned short hb = f2bf(v);
    wPh[((size_t)r * COPAD + co) * 64 + c] = hb;
    wPl[((size_t)r * COPAD + co) * 64 + c] = f2bf(v - bf2f(hb));
  }
}

// ---------------------------------------------------------------------------
// Stage 1: offset+mask convs as MFMA implicit-GEMM, split-bf16 (3 MFMA).
//   K permuted: k' = r*64 + c. Per dstep r: A = shifted window of xT
//   (contiguous, halo-safe), B = wP[r] panel. LDS/swizzle/MFMA/epilogue
//   geometry identical to round 2 (measured 0 bank conflicts).
// ---------------------------------------------------------------------------
struct StBuf { s16x8 ah0, ah1, al0, al1, bh0, bh1, bl0, bl1; };

__global__ __launch_bounds__(TCNT) void dcn_stage1(
    const unsigned short* __restrict__ xTh, const unsigned short* __restrict__ xTl,
    const unsigned short* __restrict__ wPh, const unsigned short* __restrict__ wPl,
    const float* __restrict__ b_off, const float* __restrict__ b_mod,
    float* __restrict__ ws, int b0, int nb)
{
  __shared__ unsigned short Ah[128][32], Al[128][32];
  __shared__ unsigned short Bh[128][32], Bl[128][32];

  const int t      = threadIdx.x;
  const int Mchunk = nb * HW;
  const int p0  = blockIdx.x * 128;          // chunk-local pixel base (2 rows)
  const int b   = b0 + (p0 >> 12);
  const int h0  = (p0 & (HW - 1)) >> 6;
  const int co0 = blockIdx.y * 128;

  // staging role (shared by A and B): row + 16-k half
  const int s_row = t >> 1;
  const int s_kh  = t & 1;
  const int s_sw  = ((s_row >> 1) & 3) << 3;
  const int a_h   = h0 + (s_row >> 6);       // halo row base (+ki)
  const int a_w   = s_row & 63;              // halo col base (+kj)

  const unsigned short* xbh = xTh + (size_t)b * HXW * HXW * 64;
  const unsigned short* xbl = xTl + (size_t)b * HXW * HXW * 64;

  // MFMA role
  const int wave = t >> 6, lane = t & 63;
  const int wm = wave >> 1, wn = wave & 1;
  const int lrow = lane & 15;
  const int lkh  = lane >> 4;

  f32x4 acc[4][4];
  #pragma unroll
  for (int m = 0; m < 4; ++m)
    #pragma unroll
    for (int n = 0; n < 4; ++n) acc[m][n] = (f32x4)0.f;

  StBuf bufA, bufB;

#define STAGE_LOAD(BUF, R, KSUB)                                             \
  {                                                                          \
    const int ki = (R) / 3;                                                  \
    const int kj = (R) - 3 * ki;                                             \
    const size_t aoff = ((size_t)((a_h + ki) * HXW + (a_w + kj))) * 64 +     \
                        (KSUB) * 32 + s_kh * 16;                             \
    BUF.ah0 = *(const s16x8*)(xbh + aoff);                                   \
    BUF.ah1 = *(const s16x8*)(xbh + aoff + 8);                               \
    BUF.al0 = *(const s16x8*)(xbl + aoff);                                   \
    BUF.al1 = *(const s16x8*)(xbl + aoff + 8);                               \
    const size_t boff = ((size_t)(R) * COPAD + co0 + s_row) * 64 +           \
                        (KSUB) * 32 + s_kh * 16;                             \
    BUF.bh0 = *(const s16x8*)(wPh + boff);                                   \
    BUF.bh1 = *(const s16x8*)(wPh + boff + 8);                               \
    BUF.bl0 = *(const s16x8*)(wPl + boff);                                   \
    BUF.bl1 = *(const s16x8*)(wPl + boff + 8);                               \
  }

#define STAGE_WRITE(BUF)                                                     \
  {                                                                          \
    const int c0 = (s_kh * 16) ^ s_sw;                                       \
    const int c1 = (s_kh * 16 + 8) ^ s_sw;                                   \
    *(s16x8*)&Ah[s_row][c0] = BUF.ah0;                                       \
    *(s16x8*)&Ah[s_row][c1] = BUF.ah1;                                       \
    *(s16x8*)&Al[s_row][c0] = BUF.al0;                                       \
    *(s16x8*)&Al[s_row][c1] = BUF.al1;                                       \
    *(s16x8*)&Bh[s_row][c0] = BUF.bh0;                                       \
    *(s16x8*)&Bh[s_row][c1] = BUF.bh1;                                       \
    *(s16x8*)&Bl[s_row][c0] = BUF.bl0;                                       \
    *(s16x8*)&Bl[s_row][c1] = BUF.bl1;                                       \
  }

#define MFMA_PHASE()                                                         \
  {                                                                          \
    s16x8 fah[4], fal[4];                                                    \
    _Pragma("unroll")                                                        \
    for (int m = 0; m < 4; ++m) {                                            \
      const int r   = wm * 64 + m * 16 + lrow;                               \
      const int col = (lkh * 8) ^ (((r >> 1) & 3) << 3);                     \
      fah[m] = *(const s16x8*)&Ah[r][col];                                   \
      fal[m] = *(const s16x8*)&Al[r][col];                                   \
    }                                                                        \
    _Pragma("unroll")                                                        \
    for (int n = 0; n < 4; ++n) {                                            \
      const int r   = wn * 64 + n * 16 + lrow;                               \
      const int col = (lkh * 8) ^ (((r >> 1) & 3) << 3);                     \
      const s16x8 fbh = *(const s16x8*)&Bh[r][col];                          \
      const s16x8 fbl = *(const s16x8*)&Bl[r][col];                          \
      _Pragma("unroll")                                                      \
      for (int m = 0; m < 4; ++m) {                                          \
        acc[m][n] = __builtin_amdgcn_mfma_f32_16x16x32_bf16(fah[m], fbh, acc[m][n], 0, 0, 0); \
        acc[m][n] = __builtin_amdgcn_mfma_f32_16x16x32_bf16(fah[m], fbl, acc[m][n], 0, 0, 0); \
        acc[m][n] = __builtin_amdgcn_mfma_f32_16x16x32_bf16(fal[m], fbh, acc[m][n], 0, 0, 0); \
      }                                                                      \
    }                                                                        \
  }

  STAGE_LOAD(bufA, 0, 0)
  #pragma unroll 1
  for (int r = 0; r < 9; ++r) {
    STAGE_WRITE(bufA)
    STAGE_LOAD(bufB, r, 1)             // issue next loads before barrier/MFMA
    __syncthreads();
    MFMA_PHASE()
    __syncthreads();
    STAGE_WRITE(bufB)
    if (r < 8) STAGE_LOAD(bufA, r + 1, 0)
    __syncthreads();
    MFMA_PHASE()
    __syncthreads();
  }

  // Epilogue: bias, clip (offset region), store plane-major. (round-2 verbatim)
  const bool isOff = (co0 < NOFF);           // 1152 = 9*128 -> block-uniform
  #pragma unroll
  for (int n = 0; n < 4; ++n) {
    const int cog = co0 + wn * 64 + n * 16 + lrow;
    if (cog >= NTOT) continue;
    const float bias = isOff ? b_off[cog] : b_mod[cog - NOFF];
    float* oplane = ws + (size_t)cog * Mchunk;
    #pragma unroll
    for (int m = 0; m < 4; ++m) {
      f32x4 v = acc[m][n];
      float4 o;
      o.x = v[0] + bias; o.y = v[1] + bias; o.z = v[2] + bias; o.w = v[3] + bias;
      if (isOff) {
        o.x = fminf(MAXOFF, fmaxf(-MAXOFF, o.x));
        o.y = fminf(MAXOFF, fmaxf(-MAXOFF, o.y));
        o.z = fminf(MAXOFF, fmaxf(-MAXOFF, o.z));
        o.w = fminf(MAXOFF, fmaxf(-MAXOFF, o.w));
      }
      const int pb = p0 + wm * 64 + m * 16 + lkh * 4;
      *(float4*)(oplane + pb) = o;
    }
  }
#undef STAGE_LOAD
#undef STAGE_WRITE
#undef MFMA_PHASE
}

// ---------------------------------------------------------------------------
// Stage 2: bilinear deform-sampling + output einsum, fused.
//   Now 32-pixel blocks (grid 2x) for occupancy/latency hiding.
// ---------------------------------------------------------------------------
__global__ __launch_bounds__(TCNT) void dcn_stage2(
    const float* __restrict__ x, const float* __restrict__ ws,
    const float* __restrict__ w_conv, float* __restrict__ out,
    int b0, int nb)
{
  __shared__ float samp[32][68];
  __shared__ float wlds[128][68];

  const int t      = threadIdx.x;
  const int Mchunk = nb * HW;
  const int pc0 = blockIdx.x * 32;           // half image row, chunk-local
  const int b   = b0 + (pc0 >> 12);
  const int h   = (pc0 & (HW - 1)) >> 6;
  const int w0  = pc0 & 63;                  // 0 or 32

  const int tpx = t & 31;                    // pixel within block
  const int tsg = t >> 5;                    // 0..7
  const float* ws_pix = ws + pc0 + tpx;
  const float* xb     = x + (size_t)b * CIN * HW;

  const int tp2 = t & 15;
  const int to  = t >> 4;                    // 0..15

  float acc[2][8];
  #pragma unroll
  for (int i = 0; i < 2; ++i)
    #pragma unroll
    for (int j = 0; j < 8; ++j) acc[i][j] = 0.f;

  #pragma unroll 1
  for (int sc = 0; sc < 9; ++sc) {
    __syncthreads();   // previous phase B done before overwriting samp/wlds
    // ---- phase A: samples for s in [sc*64, sc*64+64), s = c*9 + kk
    #pragma unroll 2
    for (int j = 0; j < 8; ++j) {
      const int sl = tsg + 8 * j;
      const int s  = sc * 64 + sl;
      const int c  = s / 9;
      const int kk = s - c * 9;
      const int ki = kk / 3;
      const int kj = kk - ki * 3;
      const float dy = ws_pix[(size_t)(2 * s)     * Mchunk];
      const float dx = ws_pix[(size_t)(2 * s + 1) * Mchunk];
      const float m  = ws_pix[(size_t)(NOFF + s)  * Mchunk];
      const float py = dy + (float)(h + ki - 1);
      const float px = dx + (float)(w0 + tpx + kj - 1);
      const bool valid = (py > -1.f) && (py < (float)HDIM) &&
                         (px > -1.f) && (px < (float)WDIM);
      const float y0f = floorf(py), x0f = floorf(px);
      const float wy = py - y0f, wx = px - x0f;
      const int y0 = (int)y0f, x0 = (int)x0f;
      const float* plane = xb + c * HW;
      float v00 = 0.f, v01 = 0.f, v10 = 0.f, v11 = 0.f;
      if ((unsigned)y0 < (unsigned)HDIM) {
        const float* row = plane + (y0 << 6);
        if ((unsigned)x0       < (unsigned)WDIM) v00 = row[x0];
        if ((unsigned)(x0 + 1) < (unsigned)WDIM) v01 = row[x0 + 1];
      }
      if ((unsigned)(y0 + 1) < (unsigned)HDIM) {
        const float* row = plane + ((y0 + 1) << 6);
        if ((unsigned)x0       < (unsigned)WDIM) v10 = row[x0];
        if ((unsigned)(x0 + 1) < (unsigned)WDIM) v11 = row[x0 + 1];
      }
      const float val = (1.f - wy) * ((1.f - wx) * v00 + wx * v01)
                      + wy         * ((1.f - wx) * v10 + wx * v11);
      samp[tpx][sl] = valid ? val * m : 0.f;
    }
    // ---- stage w_conv chunk: wlds[o][0..63] = w_conv[o][sc*64 .. +63]
    #pragma unroll
    for (int i = 0; i < 8; ++i) {
      const int lin = t + TCNT * i;          // 0..2047
      const int o   = lin >> 4;
      const int f4  = (lin & 15) << 2;
      *(float4*)&wlds[o][f4] =
          *(const float4*)(w_conv + (size_t)o * KD + sc * 64 + f4);
    }
    __syncthreads();
    // ---- phase B: acc[px_rep][o_rep] += samp . wlds
    #pragma unroll 4
    for (int s4 = 0; s4 < 16; ++s4) {
      float4 av[2];
      av[0] = *(const float4*)&samp[tp2][s4 * 4];
      av[1] = *(const float4*)&samp[tp2 + 16][s4 * 4];
      #pragma unroll
      for (int j = 0; j < 8; ++j) {
        const float4 wv = *(const float4*)&wlds[to + 16 * j][s4 * 4];
        acc[0][j] += av[0].x * wv.x + av[0].y * wv.y
                   + av[0].z * wv.z + av[0].w * wv.w;
        acc[1][j] += av[1].x * wv.x + av[1].y * wv.y
                   + av[1].z * wv.z + av[1].w * wv.w;
      }
    }
  }

  #pragma unroll
  for (int j = 0; j < 8; ++j) {
    const int o = to + 16 * j;
    float* orow = out + ((size_t)(b * COUT + o)) * HW + h * WDIM + w0;
    orow[tp2]      = acc[0][j];
    orow[tp2 + 16] = acc[1][j];
  }
}

// ---------------------------------------------------------------------------
extern "C" void kernel_launch(void* const* d_in, const int* in_sizes, int n_in,
                              void* d_out, int out_size, void* d_ws, size_t ws_size,
                              hipStream_t stream) {
  (void)in_sizes; (void)n_in; (void)out_size;
  const float* x      = (const float*)d_in[0];
  const float* w_off  = (const float*)d_in[1];
  const float* b_off  = (const float*)d_in[2];
  const float* w_mod  = (const float*)d_in[3];
  const float* b_mod  = (const float*)d_in[4];
  const float* w_conv = (const float*)d_in[5];
  float* out = (float*)d_out;

  unsigned short* wsu = (unsigned short*)d_ws;
  unsigned short* xTh = wsu + OFF_XTH;
  unsigned short* xTl = wsu + OFF_XTL;
  unsigned short* wPh = wsu + OFF_WPH;
  unsigned short* wPl = wsu + OFF_WPL;
  float* planes = (float*)((char*)d_ws + FIXED_BYTES);

  const size_t ws_per_batch = (size_t)NTOT * HW * sizeof(float);  // 28.3 MB
  size_t avail = (ws_size > FIXED_BYTES) ? (ws_size - FIXED_BYTES) : 0;
  int nb = (int)(avail / ws_per_batch);
  if (nb < 1) nb = 1;
  if (nb > NBATCH) nb = NBATCH;

  prep_x<<<dim3(HXW, NBATCH), TCNT, 0, stream>>>(x, xTh, xTl);
  prep_w<<<COPAD, TCNT, 0, stream>>>(w_off, w_mod, wPh, wPl);

  for (int b0 = 0; b0 < NBATCH; b0 += nb) {
    const int cur = (NBATCH - b0 < nb) ? (NBATCH - b0) : nb;
    dim3 g1(cur * 32, 14);   // pixel tiles x co tiles (14*128 = 1792 >= 1728)
    dcn_stage1<<<g1, TCNT, 0, stream>>>(xTh, xTl, wPh, wPl, b_off, b_mod,
                                        planes, b0, cur);
    dcn_stage2<<<cur * 128, TCNT, 0, stream>>>(x, planes, w_conv, out, b0, cur);
  }
}

// Round 4
// 384.904 us; speedup vs baseline: 2.7541x; 1.1696x over previous
//
#include <hip/hip_runtime.h>
#include <cstddef>
#include <cstdint>

#define TCNT 256

namespace {
constexpr int CIN    = 64;
constexpr int COUT   = 128;
constexpr int HDIM   = 64;
constexpr int WDIM   = 64;
constexpr int HW     = HDIM * WDIM;     // 4096
constexpr int KD     = CIN * 9;         // 576
constexpr int NOFF   = 2 * CIN * 9;     // 1152
constexpr int NTOT   = NOFF + CIN * 9;  // 1728
constexpr int NBATCH = 8;
constexpr int HXW    = 66;              // halo-padded spatial dim
constexpr int COPAD  = 1792;            // 14*128 padded co
constexpr float MAXOFF = 16.0f;         // max(H,W)/4

// d_ws layout (ushort elements for the bf16 region, then fp32 planes)
constexpr size_t XT_ELEMS = (size_t)NBATCH * HXW * HXW * 64;  // 2,230,272
constexpr size_t WP_ELEMS = (size_t)9 * COPAD * 64;           // 1,032,192
constexpr size_t WC_ELEMS = (size_t)COUT * KD;                // 73,728
constexpr size_t OFF_XTH  = 0;
constexpr size_t OFF_XTL  = XT_ELEMS;
constexpr size_t OFF_WPH  = 2 * XT_ELEMS;
constexpr size_t OFF_WPL  = 2 * XT_ELEMS + WP_ELEMS;
constexpr size_t OFF_WCH  = 2 * XT_ELEMS + 2 * WP_ELEMS;
constexpr size_t OFF_WCL  = OFF_WCH + WC_ELEMS;
constexpr size_t FIXED_BYTES = (2 * XT_ELEMS + 2 * WP_ELEMS + 2 * WC_ELEMS) * 2;
}

typedef __attribute__((ext_vector_type(8))) short s16x8;
typedef __attribute__((ext_vector_type(4))) float f32x4;

__device__ __forceinline__ unsigned short f2bf(float v) {
  unsigned u = __builtin_bit_cast(unsigned, v);
  unsigned r = u + 0x7fffu + ((u >> 16) & 1u);   // RNE
  return (unsigned short)(r >> 16);
}
__device__ __forceinline__ float bf2f(unsigned short h) {
  unsigned u = ((unsigned)h) << 16;
  return __builtin_bit_cast(float, u);
}

// ---------------------------------------------------------------------------
// prep_x: x fp32 NCHW -> xTh/xTl bf16 hi/lo, HWC layout with zero halo:
//   xT[b][yy 0..65][xx 0..65][c 0..63], yy/xx = image coords + 1.
// ---------------------------------------------------------------------------
__global__ __launch_bounds__(TCNT) void prep_x(
    const float* __restrict__ x, unsigned short* __restrict__ xTh,
    unsigned short* __restrict__ xTl)
{
  const int b  = blockIdx.y;
  const int yy = blockIdx.x;
  const int t  = threadIdx.x;
  unsigned short* oh = xTh + ((size_t)(b * HXW + yy)) * HXW * 64;
  unsigned short* ol = xTl + ((size_t)(b * HXW + yy)) * HXW * 64;
  if (yy == 0 || yy == HXW - 1) {
    for (int lin = t; lin < HXW * 64; lin += TCNT) { oh[lin] = 0; ol[lin] = 0; }
    return;
  }
  __shared__ float tile[64][65];
  const int y = yy - 1;
  #pragma unroll
  for (int i = 0; i < 4; ++i) {
    const int f = t + TCNT * i;          // 0..1023 float4s
    const int c = f >> 4, xq = f & 15;
    const float4 v =
        *(const float4*)(x + ((size_t)(b * 64 + c)) * HW + y * WDIM + xq * 4);
    tile[c][xq * 4 + 0] = v.x; tile[c][xq * 4 + 1] = v.y;
    tile[c][xq * 4 + 2] = v.z; tile[c][xq * 4 + 3] = v.w;
  }
  if (t < 128) {                          // zero halo columns xx=0, xx=65
    const int c = t & 63, xe = (t >> 6) ? (HXW - 1) * 64 : 0;
    oh[xe + c] = 0; ol[xe + c] = 0;
  }
  __syncthreads();
  const int xc = t >> 2, cg = (t & 3) * 16;
  s16x8 h0, h1, l0, l1;
  #pragma unroll
  for (int u = 0; u < 8; ++u) {
    const float v = tile[cg + u][xc];
    const unsigned short hb = f2bf(v);
    h0[u] = (short)hb; l0[u] = (short)f2bf(v - bf2f(hb));
  }
  #pragma unroll
  for (int u = 0; u < 8; ++u) {
    const float v = tile[cg + 8 + u][xc];
    const unsigned short hb = f2bf(v);
    h1[u] = (short)hb; l1[u] = (short)f2bf(v - bf2f(hb));
  }
  *(s16x8*)(oh + (xc + 1) * 64 + cg)     = h0;
  *(s16x8*)(oh + (xc + 1) * 64 + cg + 8) = h1;
  *(s16x8*)(ol + (xc + 1) * 64 + cg)     = l0;
  *(s16x8*)(ol + (xc + 1) * 64 + cg + 8) = l1;
}

// ---------------------------------------------------------------------------
// prep_w: w_off/w_mod fp32 [co][c*9+r] -> wPh/wPl bf16 hi/lo, tap-major:
//   wP[r][co 0..1791][c 0..63], co>=1728 zero-filled.
// ---------------------------------------------------------------------------
__global__ __launch_bounds__(TCNT) void prep_w(
    const float* __restrict__ w_off, const float* __restrict__ w_mod,
    unsigned short* __restrict__ wPh, unsigned short* __restrict__ wPl)
{
  const int co = blockIdx.x;
  const int t  = threadIdx.x;
  const float* wrow = (co < NOFF) ? (w_off + (size_t)co * KD)
                    : (co < NTOT) ? (w_mod + (size_t)(co - NOFF) * KD)
                                  : nullptr;
  for (int lin = t; lin < KD; lin += TCNT) {
    const int r = lin >> 6, c = lin & 63;
    const float v = wrow ? wrow[c * 9 + r] : 0.f;
    const unsigned short hb = f2bf(v);
    wPh[((size_t)r * COPAD + co) * 64 + c] = hb;
    wPl[((size_t)r * COPAD + co) * 64 + c] = f2bf(v - bf2f(hb));
  }
}

// ---------------------------------------------------------------------------
// prep_wc: w_conv fp32 [o][576] -> wCh/wCl bf16 hi/lo, same layout.
// ---------------------------------------------------------------------------
__global__ __launch_bounds__(TCNT) void prep_wc(
    const float* __restrict__ w_conv, unsigned short* __restrict__ wCh,
    unsigned short* __restrict__ wCl)
{
  const int o = blockIdx.x;
  const int t = threadIdx.x;
  for (int lin = t; lin < KD; lin += TCNT) {
    const float v = w_conv[(size_t)o * KD + lin];
    const unsigned short hb = f2bf(v);
    wCh[(size_t)o * KD + lin] = hb;
    wCl[(size_t)o * KD + lin] = f2bf(v - bf2f(hb));
  }
}

// ---------------------------------------------------------------------------
// Stage 1: offset+mask convs as MFMA implicit-GEMM, split-bf16 (3 MFMA).
//   (unchanged from round 3: 41.7% MfmaUtil, 0 bank conflicts)
// ---------------------------------------------------------------------------
struct StBuf { s16x8 ah0, ah1, al0, al1, bh0, bh1, bl0, bl1; };

__global__ __launch_bounds__(TCNT) void dcn_stage1(
    const unsigned short* __restrict__ xTh, const unsigned short* __restrict__ xTl,
    const unsigned short* __restrict__ wPh, const unsigned short* __restrict__ wPl,
    const float* __restrict__ b_off, const float* __restrict__ b_mod,
    float* __restrict__ ws, int b0, int nb)
{
  __shared__ unsigned short Ah[128][32], Al[128][32];
  __shared__ unsigned short Bh[128][32], Bl[128][32];

  const int t      = threadIdx.x;
  const int Mchunk = nb * HW;
  const int p0  = blockIdx.x * 128;          // chunk-local pixel base (2 rows)
  const int b   = b0 + (p0 >> 12);
  const int h0  = (p0 & (HW - 1)) >> 6;
  const int co0 = blockIdx.y * 128;

  const int s_row = t >> 1;
  const int s_kh  = t & 1;
  const int s_sw  = ((s_row >> 1) & 3) << 3;
  const int a_h   = h0 + (s_row >> 6);       // halo row base (+ki)
  const int a_w   = s_row & 63;              // halo col base (+kj)

  const unsigned short* xbh = xTh + (size_t)b * HXW * HXW * 64;
  const unsigned short* xbl = xTl + (size_t)b * HXW * HXW * 64;

  const int wave = t >> 6, lane = t & 63;
  const int wm = wave >> 1, wn = wave & 1;
  const int lrow = lane & 15;
  const int lkh  = lane >> 4;

  f32x4 acc[4][4];
  #pragma unroll
  for (int m = 0; m < 4; ++m)
    #pragma unroll
    for (int n = 0; n < 4; ++n) acc[m][n] = (f32x4)0.f;

  StBuf bufA, bufB;

#define STAGE_LOAD(BUF, R, KSUB)                                             \
  {                                                                          \
    const int ki = (R) / 3;                                                  \
    const int kj = (R) - 3 * ki;                                             \
    const size_t aoff = ((size_t)((a_h + ki) * HXW + (a_w + kj))) * 64 +     \
                        (KSUB) * 32 + s_kh * 16;                             \
    BUF.ah0 = *(const s16x8*)(xbh + aoff);                                   \
    BUF.ah1 = *(const s16x8*)(xbh + aoff + 8);                               \
    BUF.al0 = *(const s16x8*)(xbl + aoff);                                   \
    BUF.al1 = *(const s16x8*)(xbl + aoff + 8);                               \
    const size_t boff = ((size_t)(R) * COPAD + co0 + s_row) * 64 +           \
                        (KSUB) * 32 + s_kh * 16;                             \
    BUF.bh0 = *(const s16x8*)(wPh + boff);                                   \
    BUF.bh1 = *(const s16x8*)(wPh + boff + 8);                               \
    BUF.bl0 = *(const s16x8*)(wPl + boff);                                   \
    BUF.bl1 = *(const s16x8*)(wPl + boff + 8);                               \
  }

#define STAGE_WRITE(BUF)                                                     \
  {                                                                          \
    const int c0 = (s_kh * 16) ^ s_sw;                                       \
    const int c1 = (s_kh * 16 + 8) ^ s_sw;                                   \
    *(s16x8*)&Ah[s_row][c0] = BUF.ah0;                                       \
    *(s16x8*)&Ah[s_row][c1] = BUF.ah1;                                       \
    *(s16x8*)&Al[s_row][c0] = BUF.al0;                                       \
    *(s16x8*)&Al[s_row][c1] = BUF.al1;                                       \
    *(s16x8*)&Bh[s_row][c0] = BUF.bh0;                                       \
    *(s16x8*)&Bh[s_row][c1] = BUF.bh1;                                       \
    *(s16x8*)&Bl[s_row][c0] = BUF.bl0;                                       \
    *(s16x8*)&Bl[s_row][c1] = BUF.bl1;                                       \
  }

#define MFMA_PHASE()                                                         \
  {                                                                          \
    s16x8 fah[4], fal[4];                                                    \
    _Pragma("unroll")                                                        \
    for (int m = 0; m < 4; ++m) {                                            \
      const int r   = wm * 64 + m * 16 + lrow;                               \
      const int col = (lkh * 8) ^ (((r >> 1) & 3) << 3);                     \
      fah[m] = *(const s16x8*)&Ah[r][col];                                   \
      fal[m] = *(const s16x8*)&Al[r][col];                                   \
    }                                                                        \
    _Pragma("unroll")                                                        \
    for (int n = 0; n < 4; ++n) {                                            \
      const int r   = wn * 64 + n * 16 + lrow;                               \
      const int col = (lkh * 8) ^ (((r >> 1) & 3) << 3);                     \
      const s16x8 fbh = *(const s16x8*)&Bh[r][col];                          \
      const s16x8 fbl = *(const s16x8*)&Bl[r][col];                          \
      _Pragma("unroll")                                                      \
      for (int m = 0; m < 4; ++m) {                                          \
        acc[m][n] = __builtin_amdgcn_mfma_f32_16x16x32_bf16(fah[m], fbh, acc[m][n], 0, 0, 0); \
        acc[m][n] = __builtin_amdgcn_mfma_f32_16x16x32_bf16(fah[m], fbl, acc[m][n], 0, 0, 0); \
        acc[m][n] = __builtin_amdgcn_mfma_f32_16x16x32_bf16(fal[m], fbh, acc[m][n], 0, 0, 0); \
      }                                                                      \
    }                                                                        \
  }

  STAGE_LOAD(bufA, 0, 0)
  #pragma unroll 1
  for (int r = 0; r < 9; ++r) {
    STAGE_WRITE(bufA)
    STAGE_LOAD(bufB, r, 1)
    __syncthreads();
    MFMA_PHASE()
    __syncthreads();
    STAGE_WRITE(bufB)
    if (r < 8) STAGE_LOAD(bufA, r + 1, 0)
    __syncthreads();
    MFMA_PHASE()
    __syncthreads();
  }

  const bool isOff = (co0 < NOFF);
  #pragma unroll
  for (int n = 0; n < 4; ++n) {
    const int cog = co0 + wn * 64 + n * 16 + lrow;
    if (cog >= NTOT) continue;
    const float bias = isOff ? b_off[cog] : b_mod[cog - NOFF];
    float* oplane = ws + (size_t)cog * Mchunk;
    #pragma unroll
    for (int m = 0; m < 4; ++m) {
      f32x4 v = acc[m][n];
      float4 o;
      o.x = v[0] + bias; o.y = v[1] + bias; o.z = v[2] + bias; o.w = v[3] + bias;
      if (isOff) {
        o.x = fminf(MAXOFF, fmaxf(-MAXOFF, o.x));
        o.y = fminf(MAXOFF, fmaxf(-MAXOFF, o.y));
        o.z = fminf(MAXOFF, fmaxf(-MAXOFF, o.z));
        o.w = fminf(MAXOFF, fmaxf(-MAXOFF, o.w));
      }
      const int pb = p0 + wm * 64 + m * 16 + lkh * 4;
      *(float4*)(oplane + pb) = o;
    }
  }
#undef STAGE_LOAD
#undef STAGE_WRITE
#undef MFMA_PHASE
}

// ---------------------------------------------------------------------------
// Stage 2 (v2): bilinear deform-sampling fp32 + einsum on MFMA (split-bf16).
//   Block = 32 pixels x 128 outs, 4 waves each 32px x 32out.
//   Per sc (64 K): phase A computes 32x64 samples -> swizzled hi/lo LDS;
//   W chunk copied to swizzled hi/lo LDS; MFMA 24/wave (3-term split).
// ---------------------------------------------------------------------------
__global__ __launch_bounds__(TCNT) void dcn_stage2(
    const float* __restrict__ x, const float* __restrict__ planes,
    const unsigned short* __restrict__ wCh, const unsigned short* __restrict__ wCl,
    float* __restrict__ out, int b0, int nb)
{
  __shared__ unsigned short SH[32][64], SL[32][64];   // samples hi/lo
  __shared__ unsigned short WH[128][64], WL[128][64]; // w_conv chunk hi/lo

  const int t      = threadIdx.x;
  const int Mchunk = nb * HW;
  const int pc0 = blockIdx.x * 32;           // chunk-local pixel base
  const int b   = b0 + (pc0 >> 12);
  const int h   = (pc0 & (HW - 1)) >> 6;
  const int w0  = pc0 & 63;                  // 0 or 32

  // phase-A role: 8 consecutive sl per thread, fixed pixel
  const int tpx = t & 31;
  const int tsg = t >> 5;                    // 0..7 -> sl block of 8
  const int a_swz = (tpx & 7) << 3;
  const float* ws_pix = planes + pc0 + tpx;
  const float* xb     = x + (size_t)b * CIN * HW;

  // MFMA role
  const int wave = t >> 6, lane = t & 63;
  const int lrow = lane & 15, lkh = lane >> 4;
  const int f_swz = (lrow & 7) << 3;

  f32x4 acc[2][2];
  #pragma unroll
  for (int m = 0; m < 2; ++m)
    #pragma unroll
    for (int n = 0; n < 2; ++n) acc[m][n] = (f32x4)0.f;

  #pragma unroll 1
  for (int sc = 0; sc < 9; ++sc) {
    __syncthreads();   // prior MFMA done before overwriting LDS
    // ---- phase A: fp32 sampling (semantics identical to passing version)
    float vals[8];
    #pragma unroll
    for (int j = 0; j < 8; ++j) {
      const int sl = tsg * 8 + j;
      const int s  = sc * 64 + sl;
      const int c  = s / 9;
      const int kk = s - c * 9;
      const int ki = kk / 3;
      const int kj = kk - ki * 3;
      const float dy = ws_pix[(size_t)(2 * s)     * Mchunk];
      const float dx = ws_pix[(size_t)(2 * s + 1) * Mchunk];
      const float m  = ws_pix[(size_t)(NOFF + s)  * Mchunk];
      const float py = dy + (float)(h + ki - 1);
      const float px = dx + (float)(w0 + tpx + kj - 1);
      const bool valid = (py > -1.f) && (py < (float)HDIM) &&
                         (px > -1.f) && (px < (float)WDIM);
      const float y0f = floorf(py), x0f = floorf(px);
      const float wy = py - y0f, wx = px - x0f;
      const int y0 = (int)y0f, x0 = (int)x0f;
      const float* plane = xb + c * HW;
      float v00 = 0.f, v01 = 0.f, v10 = 0.f, v11 = 0.f;
      if ((unsigned)y0 < (unsigned)HDIM) {
        const float* row = plane + (y0 << 6);
        if ((unsigned)x0       < (unsigned)WDIM) v00 = row[x0];
        if ((unsigned)(x0 + 1) < (unsigned)WDIM) v01 = row[x0 + 1];
      }
      if ((unsigned)(y0 + 1) < (unsigned)HDIM) {
        const float* row = plane + ((y0 + 1) << 6);
        if ((unsigned)x0       < (unsigned)WDIM) v10 = row[x0];
        if ((unsigned)(x0 + 1) < (unsigned)WDIM) v11 = row[x0 + 1];
      }
      const float val = (1.f - wy) * ((1.f - wx) * v00 + wx * v01)
                      + wy         * ((1.f - wx) * v10 + wx * v11);
      vals[j] = valid ? val * m : 0.f;
    }
    {   // pack hi/lo and write one b128 each (swizzled slot)
      s16x8 h8, l8;
      #pragma unroll
      for (int u = 0; u < 8; ++u) {
        const unsigned short hb = f2bf(vals[u]);
        h8[u] = (short)hb;
        l8[u] = (short)f2bf(vals[u] - bf2f(hb));
      }
      const int col = (tsg * 8) ^ a_swz;
      *(s16x8*)&SH[tpx][col] = h8;
      *(s16x8*)&SL[tpx][col] = l8;
    }
    // ---- stage w_conv chunk: WH/WL[o][0..63] = wC[o][sc*64 .. +63]
    #pragma unroll
    for (int i = 0; i < 4; ++i) {
      const int lin  = t + TCNT * i;         // 0..1023
      const int row  = lin >> 3;
      const int slot = lin & 7;
      const size_t g = (size_t)row * KD + sc * 64 + slot * 8;
      const int col  = (slot * 8) ^ ((row & 7) << 3);
      *(s16x8*)&WH[row][col] = *(const s16x8*)(wCh + g);
      *(s16x8*)&WL[row][col] = *(const s16x8*)(wCl + g);
    }
    __syncthreads();
    // ---- MFMA: 2 k-subchunks of 32
    #pragma unroll
    for (int ks = 0; ks < 2; ++ks) {
      const int kb = ks * 32 + lkh * 8;
      s16x8 fah[2], fal[2];
      #pragma unroll
      for (int m = 0; m < 2; ++m) {
        const int r   = m * 16 + lrow;
        const int col = kb ^ f_swz;
        fah[m] = *(const s16x8*)&SH[r][col];
        fal[m] = *(const s16x8*)&SL[r][col];
      }
      #pragma unroll
      for (int n = 0; n < 2; ++n) {
        const int r   = wave * 32 + n * 16 + lrow;
        const int col = kb ^ f_swz;
        const s16x8 fbh = *(const s16x8*)&WH[r][col];
        const s16x8 fbl = *(const s16x8*)&WL[r][col];
        #pragma unroll
        for (int m = 0; m < 2; ++m) {
          acc[m][n] = __builtin_amdgcn_mfma_f32_16x16x32_bf16(fah[m], fbh, acc[m][n], 0, 0, 0);
          acc[m][n] = __builtin_amdgcn_mfma_f32_16x16x32_bf16(fah[m], fbl, acc[m][n], 0, 0, 0);
          acc[m][n] = __builtin_amdgcn_mfma_f32_16x16x32_bf16(fal[m], fbh, acc[m][n], 0, 0, 0);
        }
      }
    }
  }

  // Epilogue: D col(lane&15) = out-channel, row((lane>>4)*4+reg) = pixel.
  #pragma unroll
  for (int n = 0; n < 2; ++n) {
    const int o = wave * 32 + n * 16 + lrow;
    float* obase = out + ((size_t)(b * COUT + o)) * HW + h * WDIM + w0;
    #pragma unroll
    for (int m = 0; m < 2; ++m) {
      const int pxl = m * 16 + lkh * 4;
      f32x4 v = acc[m][n];
      *(float4*)(obase + pxl) = make_float4(v[0], v[1], v[2], v[3]);
    }
  }
}

// ---------------------------------------------------------------------------
extern "C" void kernel_launch(void* const* d_in, const int* in_sizes, int n_in,
                              void* d_out, int out_size, void* d_ws, size_t ws_size,
                              hipStream_t stream) {
  (void)in_sizes; (void)n_in; (void)out_size;
  const float* x      = (const float*)d_in[0];
  const float* w_off  = (const float*)d_in[1];
  const float* b_off  = (const float*)d_in[2];
  const float* w_mod  = (const float*)d_in[3];
  const float* b_mod  = (const float*)d_in[4];
  const float* w_conv = (const float*)d_in[5];
  float* out = (float*)d_out;

  unsigned short* wsu = (unsigned short*)d_ws;
  unsigned short* xTh = wsu + OFF_XTH;
  unsigned short* xTl = wsu + OFF_XTL;
  unsigned short* wPh = wsu + OFF_WPH;
  unsigned short* wPl = wsu + OFF_WPL;
  unsigned short* wCh = wsu + OFF_WCH;
  unsigned short* wCl = wsu + OFF_WCL;
  float* planes = (float*)((char*)d_ws + FIXED_BYTES);

  const size_t ws_per_batch = (size_t)NTOT * HW * sizeof(float);  // 28.3 MB
  size_t avail = (ws_size > FIXED_BYTES) ? (ws_size - FIXED_BYTES) : 0;
  int nb = (int)(avail / ws_per_batch);
  if (nb < 1) nb = 1;
  if (nb > NBATCH) nb = NBATCH;

  prep_x<<<dim3(HXW, NBATCH), TCNT, 0, stream>>>(x, xTh, xTl);
  prep_w<<<COPAD, TCNT, 0, stream>>>(w_off, w_mod, wPh, wPl);
  prep_wc<<<COUT, TCNT, 0, stream>>>(w_conv, wCh, wCl);

  for (int b0 = 0; b0 < NBATCH; b0 += nb) {
    const int cur = (NBATCH - b0 < nb) ? (NBATCH - b0) : nb;
    dim3 g1(cur * 32, 14);   // pixel tiles x co tiles (14*128 = 1792 >= 1728)
    dcn_stage1<<<g1, TCNT, 0, stream>>>(xTh, xTl, wPh, wPl, b_off, b_mod,
                                        planes, b0, cur);
    dcn_stage2<<<cur * 128, TCNT, 0, stream>>>(x, planes, wCh, wCl, out, b0, cur);
  }
}

// Round 6
// 327.033 us; speedup vs baseline: 3.2415x; 1.1770x over previous
//
#include <hip/hip_runtime.h>
#include <cstddef>
#include <cstdint>

#define TCNT 256

namespace {
constexpr int CIN    = 64;
constexpr int COUT   = 128;
constexpr int HDIM   = 64;
constexpr int WDIM   = 64;
constexpr int HW     = HDIM * WDIM;     // 4096
constexpr int KD     = CIN * 9;         // 576
constexpr int NOFF   = 2 * CIN * 9;     // 1152
constexpr int NTOT   = NOFF + CIN * 9;  // 1728
constexpr int NBATCH = 8;
constexpr int HXW    = 66;              // halo-padded spatial dim
constexpr int COPAD  = 1792;            // 14*128 padded co
constexpr float MAXOFF = 16.0f;         // max(H,W)/4

// d_ws layout (ushort elements for the fp16 region, then fp32 planes)
constexpr size_t XT_ELEMS = (size_t)NBATCH * HXW * HXW * 64;  // hi only
constexpr size_t WP_ELEMS = (size_t)9 * COPAD * 64;
constexpr size_t WC_ELEMS = (size_t)COUT * KD;
constexpr size_t OFF_XFH  = 0;
constexpr size_t OFF_WPH  = XT_ELEMS;
constexpr size_t OFF_WPL  = XT_ELEMS + WP_ELEMS;
constexpr size_t OFF_WCH  = XT_ELEMS + 2 * WP_ELEMS;
constexpr size_t FIXED_BYTES = (XT_ELEMS + 2 * WP_ELEMS + WC_ELEMS) * 2;
}

typedef __attribute__((ext_vector_type(8))) short    s16x8;
typedef __attribute__((ext_vector_type(8))) _Float16 f16x8;
typedef __attribute__((ext_vector_type(4))) float    f32x4;

__device__ __forceinline__ unsigned short f2h(float v) {
  _Float16 h = (_Float16)v;                       // RNE
  return __builtin_bit_cast(unsigned short, h);
}
__device__ __forceinline__ float h2f(unsigned short u) {
  return (float)__builtin_bit_cast(_Float16, u);
}

// ---------------------------------------------------------------------------
// prep_x: x fp32 NCHW -> xFh fp16 (truncated operand), HWC with zero halo:
//   xF[b][yy 0..65][xx 0..65][c 0..63].
// ---------------------------------------------------------------------------
__global__ __launch_bounds__(TCNT) void prep_x(
    const float* __restrict__ x, unsigned short* __restrict__ xFh)
{
  const int b  = blockIdx.y;
  const int yy = blockIdx.x;
  const int t  = threadIdx.x;
  unsigned short* oh = xFh + ((size_t)(b * HXW + yy)) * HXW * 64;
  if (yy == 0 || yy == HXW - 1) {
    for (int lin = t; lin < HXW * 64; lin += TCNT) oh[lin] = 0;
    return;
  }
  __shared__ float tile[64][65];
  const int y = yy - 1;
  #pragma unroll
  for (int i = 0; i < 4; ++i) {
    const int f = t + TCNT * i;          // 0..1023 float4s
    const int c = f >> 4, xq = f & 15;
    const float4 v =
        *(const float4*)(x + ((size_t)(b * 64 + c)) * HW + y * WDIM + xq * 4);
    tile[c][xq * 4 + 0] = v.x; tile[c][xq * 4 + 1] = v.y;
    tile[c][xq * 4 + 2] = v.z; tile[c][xq * 4 + 3] = v.w;
  }
  if (t < 128) {                          // zero halo columns xx=0, xx=65
    const int c = t & 63, xe = (t >> 6) ? (HXW - 1) * 64 : 0;
    oh[xe + c] = 0;
  }
  __syncthreads();
  const int xc = t >> 2, cg = (t & 3) * 16;
  s16x8 h0, h1;
  #pragma unroll
  for (int u = 0; u < 8; ++u) h0[u] = (short)f2h(tile[cg + u][xc]);
  #pragma unroll
  for (int u = 0; u < 8; ++u) h1[u] = (short)f2h(tile[cg + 8 + u][xc]);
  *(s16x8*)(oh + (xc + 1) * 64 + cg)     = h0;
  *(s16x8*)(oh + (xc + 1) * 64 + cg + 8) = h1;
}

// ---------------------------------------------------------------------------
// prep_w: w_off/w_mod fp32 [co][c*9+r] -> wPh/wPl fp16 hi/lo, tap-major:
//   wP[r][co 0..1791][c 0..63], co>=1728 zero-filled.
// ---------------------------------------------------------------------------
__global__ __launch_bounds__(TCNT) void prep_w(
    const float* __restrict__ w_off, const float* __restrict__ w_mod,
    unsigned short* __restrict__ wPh, unsigned short* __restrict__ wPl)
{
  const int co = blockIdx.x;
  const int t  = threadIdx.x;
  const float* wrow = (co < NOFF) ? (w_off + (size_t)co * KD)
                    : (co < NTOT) ? (w_mod + (size_t)(co - NOFF) * KD)
                                  : nullptr;
  for (int lin = t; lin < KD; lin += TCNT) {
    const int r = lin >> 6, c = lin & 63;
    const float v = wrow ? wrow[c * 9 + r] : 0.f;
    const unsigned short hb = f2h(v);
    wPh[((size_t)r * COPAD + co) * 64 + c] = hb;
    wPl[((size_t)r * COPAD + co) * 64 + c] = f2h(v - h2f(hb));
  }
}

// ---------------------------------------------------------------------------
// prep_wc: w_conv fp32 [o][576] -> wCh fp16 (truncated operand).
// ---------------------------------------------------------------------------
__global__ __launch_bounds__(TCNT) void prep_wc(
    const float* __restrict__ w_conv, unsigned short* __restrict__ wCh)
{
  const int o = blockIdx.x;
  const int t = threadIdx.x;
  for (int lin = t; lin < KD; lin += TCNT)
    wCh[(size_t)o * KD + lin] = f2h(w_conv[(size_t)o * KD + lin]);
}

// ---------------------------------------------------------------------------
// Stage 1: offset+mask convs as MFMA implicit-GEMM, fp16 2-term:
//   C = A*(Bh+Bl), A = fp16(im2col(x)) truncated, B = weights hi/lo split.
//   Geometry identical to round-4 (41.7% MfmaUtil, 0 bank conflicts).
// ---------------------------------------------------------------------------
struct StBuf { s16x8 ah0, ah1, bh0, bh1, bl0, bl1; };

__global__ __launch_bounds__(TCNT) void dcn_stage1(
    const unsigned short* __restrict__ xFh,
    const unsigned short* __restrict__ wPh, const unsigned short* __restrict__ wPl,
    const float* __restrict__ b_off, const float* __restrict__ b_mod,
    float* __restrict__ ws, int b0, int nb)
{
  __shared__ unsigned short Ah[128][32];
  __shared__ unsigned short Bh[128][32], Bl[128][32];

  const int t      = threadIdx.x;
  const int Mchunk = nb * HW;
  const int p0  = blockIdx.x * 128;          // chunk-local pixel base (2 rows)
  const int b   = b0 + (p0 >> 12);
  const int h0  = (p0 & (HW - 1)) >> 6;
  const int co0 = blockIdx.y * 128;

  const int s_row = t >> 1;
  const int s_kh  = t & 1;
  const int s_sw  = ((s_row >> 1) & 3) << 3;
  const int a_h   = h0 + (s_row >> 6);       // halo row base (+ki)
  const int a_w   = s_row & 63;              // halo col base (+kj)

  const unsigned short* xbh = xFh + (size_t)b * HXW * HXW * 64;

  const int wave = t >> 6, lane = t & 63;
  const int wm = wave >> 1, wn = wave & 1;
  const int lrow = lane & 15;
  const int lkh  = lane >> 4;

  f32x4 acc[4][4];
  #pragma unroll
  for (int m = 0; m < 4; ++m)
    #pragma unroll
    for (int n = 0; n < 4; ++n) acc[m][n] = (f32x4)0.f;

  StBuf bufA, bufB;

#define STAGE_LOAD(BUF, R, KSUB)                                             \
  {                                                                          \
    const int ki = (R) / 3;                                                  \
    const int kj = (R) - 3 * ki;                                             \
    const size_t aoff = ((size_t)((a_h + ki) * HXW + (a_w + kj))) * 64 +     \
                        (KSUB) * 32 + s_kh * 16;                             \
    BUF.ah0 = *(const s16x8*)(xbh + aoff);                                   \
    BUF.ah1 = *(const s16x8*)(xbh + aoff + 8);                               \
    const size_t boff = ((size_t)(R) * COPAD + co0 + s_row) * 64 +           \
                        (KSUB) * 32 + s_kh * 16;                             \
    BUF.bh0 = *(const s16x8*)(wPh + boff);                                   \
    BUF.bh1 = *(const s16x8*)(wPh + boff + 8);                               \
    BUF.bl0 = *(const s16x8*)(wPl + boff);                                   \
    BUF.bl1 = *(const s16x8*)(wPl + boff + 8);                               \
  }

#define STAGE_WRITE(BUF)                                                     \
  {                                                                          \
    const int c0 = (s_kh * 16) ^ s_sw;                                       \
    const int c1 = (s_kh * 16 + 8) ^ s_sw;                                   \
    *(s16x8*)&Ah[s_row][c0] = BUF.ah0;                                       \
    *(s16x8*)&Ah[s_row][c1] = BUF.ah1;                                       \
    *(s16x8*)&Bh[s_row][c0] = BUF.bh0;                                       \
    *(s16x8*)&Bh[s_row][c1] = BUF.bh1;                                       \
    *(s16x8*)&Bl[s_row][c0] = BUF.bl0;                                       \
    *(s16x8*)&Bl[s_row][c1] = BUF.bl1;                                       \
  }

#define MFMA_PHASE()                                                         \
  {                                                                          \
    f16x8 fa[4];                                                             \
    _Pragma("unroll")                                                        \
    for (int m = 0; m < 4; ++m) {                                            \
      const int r   = wm * 64 + m * 16 + lrow;                               \
      const int col = (lkh * 8) ^ (((r >> 1) & 3) << 3);                     \
      fa[m] = *(const f16x8*)&Ah[r][col];                                    \
    }                                                                        \
    _Pragma("unroll")                                                        \
    for (int n = 0; n < 4; ++n) {                                            \
      const int r   = wn * 64 + n * 16 + lrow;                               \
      const int col = (lkh * 8) ^ (((r >> 1) & 3) << 3);                     \
      const f16x8 fbh = *(const f16x8*)&Bh[r][col];                          \
      const f16x8 fbl = *(const f16x8*)&Bl[r][col];                          \
      _Pragma("unroll")                                                      \
      for (int m = 0; m < 4; ++m) {                                          \
        acc[m][n] = __builtin_amdgcn_mfma_f32_16x16x32_f16(fa[m], fbh, acc[m][n], 0, 0, 0); \
        acc[m][n] = __builtin_amdgcn_mfma_f32_16x16x32_f16(fa[m], fbl, acc[m][n], 0, 0, 0); \
      }                                                                      \
    }                                                                        \
  }

  STAGE_LOAD(bufA, 0, 0)
  #pragma unroll 1
  for (int r = 0; r < 9; ++r) {
    STAGE_WRITE(bufA)
    STAGE_LOAD(bufB, r, 1)
    __syncthreads();
    MFMA_PHASE()
    __syncthreads();
    STAGE_WRITE(bufB)
    if (r < 8) STAGE_LOAD(bufA, r + 1, 0)
    __syncthreads();
    MFMA_PHASE()
    __syncthreads();
  }

  const bool isOff = (co0 < NOFF);
  #pragma unroll
  for (int n = 0; n < 4; ++n) {
    const int cog = co0 + wn * 64 + n * 16 + lrow;
    if (cog >= NTOT) continue;
    const float bias = isOff ? b_off[cog] : b_mod[cog - NOFF];
    float* oplane = ws + (size_t)cog * Mchunk;
    #pragma unroll
    for (int m = 0; m < 4; ++m) {
      f32x4 v = acc[m][n];
      float4 o;
      o.x = v[0] + bias; o.y = v[1] + bias; o.z = v[2] + bias; o.w = v[3] + bias;
      if (isOff) {
        o.x = fminf(MAXOFF, fmaxf(-MAXOFF, o.x));
        o.y = fminf(MAXOFF, fmaxf(-MAXOFF, o.y));
        o.z = fminf(MAXOFF, fmaxf(-MAXOFF, o.z));
        o.w = fminf(MAXOFF, fmaxf(-MAXOFF, o.w));
      }
      const int pb = p0 + wm * 64 + m * 16 + lkh * 4;
      *(float4*)(oplane + pb) = o;
    }
  }
#undef STAGE_LOAD
#undef STAGE_WRITE
#undef MFMA_PHASE
}

// ---------------------------------------------------------------------------
// Stage 2: bilinear deform-sampling fp32 + einsum on MFMA, fp16 2-term:
//   samples split hi/lo, w_conv truncated. LDS 24 KB -> higher occupancy.
// ---------------------------------------------------------------------------
__global__ __launch_bounds__(TCNT) void dcn_stage2(
    const float* __restrict__ x, const float* __restrict__ planes,
    const unsigned short* __restrict__ wCh,
    float* __restrict__ out, int b0, int nb)
{
  __shared__ unsigned short SH[32][64], SL[32][64];   // samples hi/lo
  __shared__ unsigned short WH[128][64];              // w_conv chunk (hi)

  const int t      = threadIdx.x;
  const int Mchunk = nb * HW;
  const int pc0 = blockIdx.x * 32;           // chunk-local pixel base
  const int b   = b0 + (pc0 >> 12);
  const int h   = (pc0 & (HW - 1)) >> 6;
  const int w0  = pc0 & 63;                  // 0 or 32

  const int tpx = t & 31;
  const int tsg = t >> 5;                    // 0..7 -> sl block of 8
  const int a_swz = (tpx & 7) << 3;
  const float* ws_pix = planes + pc0 + tpx;
  const float* xb     = x + (size_t)b * CIN * HW;

  const int wave = t >> 6, lane = t & 63;
  const int lrow = lane & 15, lkh = lane >> 4;
  const int f_swz = (lrow & 7) << 3;

  f32x4 acc[2][2];
  #pragma unroll
  for (int m = 0; m < 2; ++m)
    #pragma unroll
    for (int n = 0; n < 2; ++n) acc[m][n] = (f32x4)0.f;

  #pragma unroll 1
  for (int sc = 0; sc < 9; ++sc) {
    __syncthreads();   // prior MFMA done before overwriting LDS
    // ---- phase A: fp32 sampling (semantics identical to passing version)
    float vals[8];
    #pragma unroll
    for (int j = 0; j < 8; ++j) {
      const int sl = tsg * 8 + j;
      const int s  = sc * 64 + sl;
      const int c  = s / 9;
      const int kk = s - c * 9;
      const int ki = kk / 3;
      const int kj = kk - ki * 3;
      const float dy = ws_pix[(size_t)(2 * s)     * Mchunk];
      const float dx = ws_pix[(size_t)(2 * s + 1) * Mchunk];
      const float m  = ws_pix[(size_t)(NOFF + s)  * Mchunk];
      const float py = dy + (float)(h + ki - 1);
      const float px = dx + (float)(w0 + tpx + kj - 1);
      const bool valid = (py > -1.f) && (py < (float)HDIM) &&
                         (px > -1.f) && (px < (float)WDIM);
      const float y0f = floorf(py), x0f = floorf(px);
      const float wy = py - y0f, wx = px - x0f;
      const int y0 = (int)y0f, x0 = (int)x0f;
      const float* plane = xb + c * HW;
      float v00 = 0.f, v01 = 0.f, v10 = 0.f, v11 = 0.f;
      if ((unsigned)y0 < (unsigned)HDIM) {
        const float* row = plane + (y0 << 6);
        if ((unsigned)x0       < (unsigned)WDIM) v00 = row[x0];
        if ((unsigned)(x0 + 1) < (unsigned)WDIM) v01 = row[x0 + 1];
      }
      if ((unsigned)(y0 + 1) < (unsigned)HDIM) {
        const float* row = plane + ((y0 + 1) << 6);
        if ((unsigned)x0       < (unsigned)WDIM) v10 = row[x0];
        if ((unsigned)(x0 + 1) < (unsigned)WDIM) v11 = row[x0 + 1];
      }
      const float val = (1.f - wy) * ((1.f - wx) * v00 + wx * v01)
                      + wy         * ((1.f - wx) * v10 + wx * v11);
      vals[j] = valid ? val * m : 0.f;
    }
    {   // pack hi/lo fp16 and write one b128 each (swizzled slot)
      s16x8 h8, l8;
      #pragma unroll
      for (int u = 0; u < 8; ++u) {
        const unsigned short hb = f2h(vals[u]);
        h8[u] = (short)hb;
        l8[u] = (short)f2h(vals[u] - h2f(hb));
      }
      const int col = (tsg * 8) ^ a_swz;
      *(s16x8*)&SH[tpx][col] = h8;
      *(s16x8*)&SL[tpx][col] = l8;
    }
    // ---- stage w_conv chunk: WH[o][0..63] = wC[o][sc*64 .. +63]
    #pragma unroll
    for (int i = 0; i < 4; ++i) {
      const int lin  = t + TCNT * i;         // 0..1023
      const int row  = lin >> 3;
      const int slot = lin & 7;
      const size_t g = (size_t)row * KD + sc * 64 + slot * 8;
      const int col  = (slot * 8) ^ ((row & 7) << 3);
      *(s16x8*)&WH[row][col] = *(const s16x8*)(wCh + g);
    }
    __syncthreads();
    // ---- MFMA: 2 k-subchunks of 32
    #pragma unroll
    for (int ks = 0; ks < 2; ++ks) {
      const int kb = ks * 32 + lkh * 8;
      f16x8 fah[2], fal[2];
      #pragma unroll
      for (int m = 0; m < 2; ++m) {
        const int r   = m * 16 + lrow;
        const int col = kb ^ f_swz;
        fah[m] = *(const f16x8*)&SH[r][col];
        fal[m] = *(const f16x8*)&SL[r][col];
      }
      #pragma unroll
      for (int n = 0; n < 2; ++n) {
        const int r   = wave * 32 + n * 16 + lrow;
        const int col = kb ^ f_swz;
        const f16x8 fbh = *(const f16x8*)&WH[r][col];
        #pragma unroll
        for (int m = 0; m < 2; ++m) {
          acc[m][n] = __builtin_amdgcn_mfma_f32_16x16x32_f16(fah[m], fbh, acc[m][n], 0, 0, 0);
          acc[m][n] = __builtin_amdgcn_mfma_f32_16x16x32_f16(fal[m], fbh, acc[m][n], 0, 0, 0);
        }
      }
    }
  }

  // Epilogue: D col(lane&15) = out-channel, row((lane>>4)*4+reg) = pixel.
  #pragma unroll
  for (int n = 0; n < 2; ++n) {
    const int o = wave * 32 + n * 16 + lrow;
    float* obase = out + ((size_t)(b * COUT + o)) * HW + h * WDIM + w0;
    #pragma unroll
    for (int m = 0; m < 2; ++m) {
      const int pxl = m * 16 + lkh * 4;
      f32x4 v = acc[m][n];
      *(float4*)(obase + pxl) = make_float4(v[0], v[1], v[2], v[3]);
    }
  }
}

// ---------------------------------------------------------------------------
extern "C" void kernel_launch(void* const* d_in, const int* in_sizes, int n_in,
                              void* d_out, int out_size, void* d_ws, size_t ws_size,
                              hipStream_t stream) {
  (void)in_sizes; (void)n_in; (void)out_size;
  const float* x      = (const float*)d_in[0];
  const float* w_off  = (const float*)d_in[1];
  const float* b_off  = (const float*)d_in[2];
  const float* w_mod  = (const float*)d_in[3];
  const float* b_mod  = (const float*)d_in[4];
  const float* w_conv = (const float*)d_in[5];
  float* out = (float*)d_out;

  unsigned short* wsu = (unsigned short*)d_ws;
  unsigned short* xFh = wsu + OFF_XFH;
  unsigned short* wPh = wsu + OFF_WPH;
  unsigned short* wPl = wsu + OFF_WPL;
  unsigned short* wCh = wsu + OFF_WCH;
  float* planes = (float*)((char*)d_ws + FIXED_BYTES);

  const size_t ws_per_batch = (size_t)NTOT * HW * sizeof(float);  // 28.3 MB
  size_t avail = (ws_size > FIXED_BYTES) ? (ws_size - FIXED_BYTES) : 0;
  int nb = (int)(avail / ws_per_batch);
  if (nb < 1) nb = 1;
  if (nb > NBATCH) nb = NBATCH;

  prep_x<<<dim3(HXW, NBATCH), TCNT, 0, stream>>>(x, xFh);
  prep_w<<<COPAD, TCNT, 0, stream>>>(w_off, w_mod, wPh, wPl);
  prep_wc<<<COUT, TCNT, 0, stream>>>(w_conv, wCh);

  for (int b0 = 0; b0 < NBATCH; b0 += nb) {
    const int cur = (NBATCH - b0 < nb) ? (NBATCH - b0) : nb;
    dim3 g1(cur * 32, 14);   // pixel tiles x co tiles (14*128 = 1792 >= 1728)
    dcn_stage1<<<g1, TCNT, 0, stream>>>(xFh, wPh, wPl, b_off, b_mod,
                                        planes, b0, cur);
    dcn_stage2<<<cur * 128, TCNT, 0, stream>>>(x, planes, wCh, out, b0, cur);
  }
}